// Round 6
// baseline (374.503 us; speedup 1.0000x reference)
//
#include <hip/hip_runtime.h>

// ---- problem constants ----
#define TT 100
#define BB 1024
#define NI 256
#define NH 512
#define NO 10
#define GK 512                 // doubled K (hi/lo interleave)

// output layout (floats), return order: cur1, cur2, spk1, spk2, mem1, mem2
constexpr long long C1_OFF = 0;
constexpr long long C2_OFF = 52428800LL;
constexpr long long S1_OFF = 53452800LL;
constexpr long long S2_OFF = 105881600LL;
constexpr long long M1_OFF = 106905600LL;
constexpr long long M2_OFF = 159334400LL;

typedef short bf16x8 __attribute__((ext_vector_type(8)));
typedef float f32x4 __attribute__((ext_vector_type(4)));

__device__ __forceinline__ unsigned int rne_bf16(float f) {
    unsigned int u = __float_as_uint(f);
    return (u + 0x7fffu + ((u >> 16) & 1u)) >> 16;
}

// f32 -> packed [hi,lo] bf16 pair (Dekker split), bit-identical to prior rounds
__device__ __forceinline__ unsigned int pack_hilo(float f) {
    unsigned int hi = rne_bf16(f);
    float hif = __uint_as_float(hi << 16);
    float e = f - hif;
    unsigned int lo = rne_bf16(e);
    return (hi & 0xffffu) | (lo << 16);
}

__device__ __forceinline__ void pack4(uint4& d, const float4& a) {
    d.x = pack_hilo(a.x); d.y = pack_hilo(a.y); d.z = pack_hilo(a.z); d.w = pack_hilo(a.w);
}

// W element f32 {0,0.5} -> duplicated bf16 pair (exact)
__device__ __forceinline__ unsigned int dup_w(float f) {
    unsigned int hb = __float_as_uint(f) >> 16;
    return hb | (hb << 16);
}

// LDS-only barrier (proven correct R5): order ds traffic without draining the
// global store stream.
__device__ __forceinline__ void barrier_lds() {
    asm volatile("s_waitcnt lgkmcnt(0)" ::: "memory");
    __builtin_amdgcn_s_barrier();
}

// ---- zero C2 (atomic accumulation target) ----
__global__ void zero_c2_kernel(float* __restrict__ c2) {
    int i = blockIdx.x * blockDim.x + threadIdx.x;
    if (i < TT * BB * NO / 4) ((float4*)c2)[i] = float4{0.f, 0.f, 0.f, 0.f};
}

// ---- fused GEMM1 + LIF1 + partial GEMM2 (atomic) ----
// Block owns (32 b) x (64 h) for ALL t. W fragments live in REGISTERS
// (t-invariant, 64 VGPR/wave) -> zero W LDS traffic. Phases of 2 t: two
// independent MFMA accumulator chains share wreg[kt] and interleave (ILP),
// one LDS barrier per 2 t. A staged to LDS (packed hi/lo once), 4 tiles.
// Per-acc k-order identical to R4/R5 -> bit-identical c1.
__launch_bounds__(512, 1)
__global__ void fused_kernel(const float* __restrict__ x, const float* __restrict__ W1,
                             const float* __restrict__ W2, float* __restrict__ out) {
    __shared__ short Al[2][2][32][512];      // 128 KB: [phase parity][j][row][gk]
    __shared__ unsigned long long bal[2][2][8][4];
    __shared__ unsigned long long w2m_lds[NO];

    const int tid = threadIdx.x;
    const int bid = blockIdx.x;
    // XCD grouping: 8 h-chunk blocks of one b-group share an XCD (bid&7)
    const int xcd = bid & 7;
    const int j8  = bid >> 3;              // 0..31
    const int bgrp = xcd * 4 + (j8 >> 3);  // 0..31 (bijective)
    const int nc   = j8 & 7;               // 0..7
    const int b0 = bgrp * 32;
    const int n0 = nc * 64;

    const int wid = tid >> 6;              // 0..7 (2m x 4n waves)
    const int lane = tid & 63;
    const int mw = wid >> 2;               // 0..1
    const int nw = wid & 3;                // 0..3
    const int fr = lane & 15;
    const int g  = lane >> 4;              // 0..3
    const int mrow = mw * 16 + fr;
    const int nrow = nw * 16 + fr;

    // ---- prologue ----
    // W fragments -> registers, packed inline from W1 (exact for {0,0.5}).
    bf16x8 wreg[16];
    #pragma unroll
    for (int kt = 0; kt < 16; ++kt) {
        float4 wv = *(const float4*)&W1[(long long)(n0 + nrow) * NI + kt * 16 + g * 4];
        uint4 o;
        o.x = dup_w(wv.x); o.y = dup_w(wv.y); o.z = dup_w(wv.z); o.w = dup_w(wv.w);
        wreg[kt] = *(bf16x8*)&o;
    }

    if (wid == 0) {
        #pragma unroll
        for (int o = 0; o < NO; ++o)
            w2m_lds[o] = __ballot(W2[o * NH + n0 + lane] != 0.0f);
    }

    const int arow = tid >> 4;             // 0..31
    const int au0 = (tid & 15) * 4;        // first 16B unit of this thread's 64B span

    // stage t0,t1 into Al[0][0/1]
    #pragma unroll
    for (int j = 0; j < 2; ++j) {
        const float* xs = x + ((long long)j * BB + b0 + arow) * NI;
        #pragma unroll
        for (int uu = 0; uu < 4; ++uu) {
            float4 a = *(const float4*)&xs[(au0 + uu) * 4];
            uint4 pa; pack4(pa, a);
            *(uint4*)&Al[0][j][arow][(((au0 + uu) ^ (arow & 7)) * 8)] = pa;
        }
    }
    // raw prefetch of t2,t3
    float4 raw0[4], raw1[4];
    #pragma unroll
    for (int uu = 0; uu < 4; ++uu) {
        raw0[uu] = *(const float4*)&x[((long long)2 * BB + b0 + arow) * NI + (au0 + uu) * 4];
        raw1[uu] = *(const float4*)&x[((long long)3 * BB + b0 + arow) * NI + (au0 + uu) * 4];
    }
    __syncthreads();
    unsigned long long w2m_reg = (tid < 32 * NO) ? w2m_lds[tid >> 5] : 0ULL;

    float m1v[4] = {0.f, 0.f, 0.f, 0.f};

    for (int ph = 0; ph < TT / 2; ++ph) {
        const int pb = ph & 1;

        // two independent MFMA chains (t=2ph, 2ph+1) interleaved; wreg shared
        f32x4 acc0 = {0.f, 0.f, 0.f, 0.f};
        f32x4 acc1 = {0.f, 0.f, 0.f, 0.f};
        #pragma unroll
        for (int kt = 0; kt < 16; ++kt) {
            bf16x8 a0 = *(const bf16x8*)&Al[pb][0][mrow][(((kt * 4 + g) ^ (mrow & 7)) * 8)];
            bf16x8 a1 = *(const bf16x8*)&Al[pb][1][mrow][(((kt * 4 + g) ^ (mrow & 7)) * 8)];
            acc0 = __builtin_amdgcn_mfma_f32_16x16x32_bf16(a0, wreg[kt], acc0, 0, 0, 0);
            acc1 = __builtin_amdgcn_mfma_f32_16x16x32_bf16(a1, wreg[kt], acc1, 0, 0, 0);
        }

        // stage next phase's tiles (t = 2ph+2, 2ph+3) from raw regs
        if (ph + 1 < TT / 2) {
            #pragma unroll
            for (int uu = 0; uu < 4; ++uu) {
                uint4 pa; pack4(pa, raw0[uu]);
                *(uint4*)&Al[pb ^ 1][0][arow][(((au0 + uu) ^ (arow & 7)) * 8)] = pa;
            }
            #pragma unroll
            for (int uu = 0; uu < 4; ++uu) {
                uint4 pa; pack4(pa, raw1[uu]);
                *(uint4*)&Al[pb ^ 1][1][arow][(((au0 + uu) ^ (arow & 7)) * 8)] = pa;
            }
            if (ph + 2 < TT / 2) {
                #pragma unroll
                for (int uu = 0; uu < 4; ++uu) {
                    raw0[uu] = *(const float4*)&x[((long long)(2 * ph + 4) * BB + b0 + arow) * NI + (au0 + uu) * 4];
                    raw1[uu] = *(const float4*)&x[((long long)(2 * ph + 5) * BB + b0 + arow) * NI + (au0 + uu) * 4];
                }
            }
        }

        // LIF1 sequentially for t=2ph then t=2ph+1; store-only outputs
        float s1v0[4], s1v1[4];
        #pragma unroll
        for (int r = 0; r < 4; ++r) {
            float c1 = acc0[r];
            float rst = (m1v[r] > 1.0f) ? 1.0f : 0.0f;
            m1v[r] = 0.9f * m1v[r] + c1 - rst;
            s1v0[r] = (m1v[r] > 1.0f) ? 1.0f : 0.0f;
            long long ob = ((long long)(2 * ph) * BB + b0 + mw * 16 + g * 4 + r) * NH + n0 + nw * 16 + fr;
            out[C1_OFF + ob] = c1;
            out[S1_OFF + ob] = s1v0[r];
            out[M1_OFF + ob] = m1v[r];
        }
        #pragma unroll
        for (int r = 0; r < 4; ++r) {
            float c1 = acc1[r];
            float rst = (m1v[r] > 1.0f) ? 1.0f : 0.0f;
            m1v[r] = 0.9f * m1v[r] + c1 - rst;
            s1v1[r] = (m1v[r] > 1.0f) ? 1.0f : 0.0f;
            long long ob = ((long long)(2 * ph + 1) * BB + b0 + mw * 16 + g * 4 + r) * NH + n0 + nw * 16 + fr;
            out[C1_OFF + ob] = c1;
            out[S1_OFF + ob] = s1v1[r];
            out[M1_OFF + ob] = m1v[r];
        }
        #pragma unroll
        for (int r = 0; r < 4; ++r) {
            unsigned long long bm0 = __ballot(s1v0[r] != 0.0f);
            unsigned long long bm1 = __ballot(s1v1[r] != 0.0f);
            if (lane == 0) { bal[pb][0][wid][r] = bm0; bal[pb][1][wid][r] = bm1; }
        }

        barrier_lds();   // LDS handoff only; global stores stay in flight

        // partial cur2 for this h-chunk, both t's
        if (tid < 32 * NO) {
            int r = tid & 31, o = tid >> 5;
            int mwr = r >> 4, l15 = r & 15;
            #pragma unroll
            for (int j = 0; j < 2; ++j) {
                unsigned long long row64 = 0;
                #pragma unroll
                for (int nwx = 0; nwx < 4; ++nwx)
                    row64 |= ((bal[pb][j][mwr * 4 + nwx][l15 & 3] >> ((l15 >> 2) * 16)) & 0xFFFFULL)
                             << (16 * nwx);
                int cnt = __popcll(row64 & w2m_reg);
                atomicAdd(out + C2_OFF + ((long long)(2 * ph + j) * BB + b0 + r) * NO + o,
                          0.5f * (float)cnt);
            }
        }
    }
}

// ---- LIF2: m2 recurrence over completed C2 (4 MB, L3-hot) ----
__launch_bounds__(512)
__global__ void lif2_kernel(float* __restrict__ out) {
    int j = blockIdx.x * 512 + threadIdx.x;
    if (j >= BB * NO) return;
    const float* c2p = out + C2_OFF + j;
    float* s2p = out + S2_OFF + j;
    float* m2p = out + M2_OFF + j;
    const int st = BB * NO;
    float m2 = 0.f;
    float v[4];
    #pragma unroll
    for (int k = 0; k < 4; ++k) v[k] = c2p[(long long)k * st];
    for (int t = 0; t < TT; t += 4) {
        #pragma unroll
        for (int k = 0; k < 4; ++k) {
            float c2 = v[k];
            if (t + 4 + k < TT) v[k] = c2p[(long long)(t + 4 + k) * st];
            float rst = (m2 > 1.0f) ? 1.0f : 0.0f;
            m2 = 0.8f * m2 + c2 - rst;
            float s2 = (m2 > 1.0f) ? 1.0f : 0.0f;
            s2p[(long long)(t + k) * st] = s2;
            m2p[(long long)(t + k) * st] = m2;
        }
    }
}

extern "C" void kernel_launch(void* const* d_in, const int* in_sizes, int n_in,
                              void* d_out, int out_size, void* d_ws, size_t ws_size,
                              hipStream_t stream) {
    const float* x  = (const float*)d_in[0];
    const float* W1 = (const float*)d_in[1];
    const float* W2 = (const float*)d_in[2];
    float* out = (float*)d_out;

    zero_c2_kernel<<<(TT * BB * NO / 4 + 255) / 256, 256, 0, stream>>>(out + C2_OFF);
    fused_kernel<<<256, 512, 0, stream>>>(x, W1, W2, out);
    lif2_kernel<<<(BB * NO + 511) / 512, 512, 0, stream>>>(out);
}

// Round 7
// 260.223 us; speedup vs baseline: 1.4392x; 1.4392x over previous
//
#include <hip/hip_runtime.h>

// ---- problem constants ----
#define TT 100
#define BB 1024
#define NI 256
#define NH 512
#define NO 10
#define TB (TT*BB)            // 102400 rows
#define GK 512                 // doubled K (hi/lo interleave)
#define GN 512

// output layout (floats), return order: cur1, cur2, spk1, spk2, mem1, mem2
constexpr long long C1_OFF = 0;
constexpr long long C2_OFF = 52428800LL;            // + T*B*NH
constexpr long long S1_OFF = 53452800LL;            // + T*B*NO
constexpr long long S2_OFF = 105881600LL;
constexpr long long M1_OFF = 106905600LL;
constexpr long long M2_OFF = 159334400LL;

typedef short bf16x8 __attribute__((ext_vector_type(8)));
typedef float f32x4 __attribute__((ext_vector_type(4)));

// round-to-nearest-even f32 -> bf16 bits
__device__ __forceinline__ unsigned int rne_bf16(float f) {
    unsigned int u = __float_as_uint(f);
    return (u + 0x7fffu + ((u >> 16) & 1u)) >> 16;
}

// f32 -> packed [hi,lo] bf16 pair (Dekker split), bit-identical to prior rounds
__device__ __forceinline__ unsigned int pack_hilo(float f) {
    unsigned int hi = rne_bf16(f);
    float hif = __uint_as_float(hi << 16);
    float e = f - hif;
    unsigned int lo = rne_bf16(e);
    return (hi & 0xffffu) | (lo << 16);
}

__device__ __forceinline__ void pack4(uint4& d, const float4& a) {
    d.x = pack_hilo(a.x); d.y = pack_hilo(a.y); d.z = pack_hilo(a.z); d.w = pack_hilo(a.w);
}

// async global->LDS, 16B per lane; LDS dest = wave-uniform base + lane*16
__device__ __forceinline__ void gload16(const void* g, void* l) {
    __builtin_amdgcn_global_load_lds(
        (const __attribute__((address_space(1))) void*)g,
        (__attribute__((address_space(3))) void*)l, 16, 0, 0);
}

// LDS-only barrier (R5-proven correct): orders ds traffic without draining the
// global store stream (__syncthreads would emit s_waitcnt vmcnt(0)).
__device__ __forceinline__ void barrier_lds() {
    asm volatile("s_waitcnt lgkmcnt(0)" ::: "memory");
    __builtin_amdgcn_s_barrier();
}

// ---- prep: W1 (f32 {0,0.5}) -> pre-swizzled LDS-image (R2-proven) ----
__global__ void prep_w_kernel(const float* __restrict__ W1, short* __restrict__ Wimg) {
    int i = blockIdx.x * blockDim.x + threadIdx.x;
    if (i >= 4 * 16 * 128 * 4) return;
    int c16 = i & 3;
    int r   = (i >> 2) & 127;
    int kt  = (i >> 9) & 15;
    int p   = i >> 13;
    int usrc = c16 ^ ((r >> 1) & 3);
    int kbase = kt * 16 + usrc * 4;
    float4 w = *(const float4*)&W1[(long long)(p * 128 + r) * NI + kbase];
    float f[4] = {w.x, w.y, w.z, w.w};
    uint4 o;
    unsigned int* op = &o.x;
    #pragma unroll
    for (int j = 0; j < 4; ++j) {
        unsigned int hb = __float_as_uint(f[j]) >> 16;   // exact for 0 / 0.5
        op[j] = hb | (hb << 16);
    }
    ((uint4*)Wimg)[i] = o;
}

// ---- GEMM1 (byte-identical to R2's 263 µs version) ----
__launch_bounds__(256, 2)
__global__ void gemm1_kernel(const float* __restrict__ x, const short* __restrict__ Wimg,
                             float* __restrict__ C) {
    __shared__ short As[2][128][40];
    __shared__ short Ws[2][128][32];
    const int tid = threadIdx.x;
    const int bid = blockIdx.x;
    const int x8 = bid & 7;
    const int g  = bid >> 3;
    const int p  = g & 3;
    const int panel = (g >> 2) * 8 + x8;
    const int m0 = (799 - panel) * 128;    // reversed: high t written first
    const int n0 = p * 128;
    const int wid = tid >> 6;
    const int lane = tid & 63;
    const int wm = (wid >> 1) * 64;
    const int wn = (wid & 1) * 64;

    f32x4 acc[4][4] = {};

    const int srow = tid >> 2;
    const int sc4 = tid & 3;
    const long long ax0 = (long long)(m0 + srow) * NI + sc4 * 4;
    const long long ax1 = ax0 + 64LL * NI;

    const int fr = lane & 15;
    const int fk = (lane >> 4) * 8;
    const int swz = (((lane >> 4) ^ ((fr >> 1) & 3)) << 4);

    const short* wbase = Wimg + (long long)p * 16 * 4096;
    const int c0 = wid * 2;

    gload16(wbase + (c0    ) * 512 + lane * 8, (char*)&Ws[0][0][0] + (c0    ) * 1024);
    gload16(wbase + (c0 + 1) * 512 + lane * 8, (char*)&Ws[0][0][0] + (c0 + 1) * 1024);
    uint4 pa0, pa1;
    {
        float4 t0a = *(const float4*)&x[ax0];
        float4 t0b = *(const float4*)&x[ax1];
        uint4 q0, q1;
        pack4(q0, t0a); pack4(q1, t0b);
        *(uint4*)&As[0][srow][sc4 * 8]      = q0;
        *(uint4*)&As[0][srow + 64][sc4 * 8] = q1;
        float4 t1a = *(const float4*)&x[ax0 + 16];
        float4 t1b = *(const float4*)&x[ax1 + 16];
        pack4(pa0, t1a); pack4(pa1, t1b);
    }
    float4 raw0a = *(const float4*)&x[ax0 + 32];
    float4 raw0b = *(const float4*)&x[ax1 + 32];
    float4 raw1a = *(const float4*)&x[ax0 + 48];
    float4 raw1b = *(const float4*)&x[ax1 + 48];
    __syncthreads();

    #pragma unroll
    for (int kt = 0; kt < 16; ++kt) {
        const int cur = kt & 1;
        const int nxt = cur ^ 1;

        if (kt + 1 < 16) {
            const short* wt = wbase + (kt + 1) * 4096;
            gload16(wt + (c0    ) * 512 + lane * 8, (char*)&Ws[nxt][0][0] + (c0    ) * 1024);
            gload16(wt + (c0 + 1) * 512 + lane * 8, (char*)&Ws[nxt][0][0] + (c0 + 1) * 1024);
            *(uint4*)&As[nxt][srow][sc4 * 8]      = pa0;
            *(uint4*)&As[nxt][srow + 64][sc4 * 8] = pa1;
        }
        if (kt + 2 < 16) {
            if (cur == 0) { pack4(pa0, raw0a); pack4(pa1, raw0b); }
            else          { pack4(pa0, raw1a); pack4(pa1, raw1b); }
        }
        if (kt + 4 < 16) {
            if (cur == 0) {
                raw0a = *(const float4*)&x[ax0 + (long long)(kt + 4) * 16];
                raw0b = *(const float4*)&x[ax1 + (long long)(kt + 4) * 16];
            } else {
                raw1a = *(const float4*)&x[ax0 + (long long)(kt + 4) * 16];
                raw1b = *(const float4*)&x[ax1 + (long long)(kt + 4) * 16];
            }
        }

        bf16x8 af[4], wf[4];
        #pragma unroll
        for (int i = 0; i < 4; ++i) {
            af[i] = *(const bf16x8*)&As[cur][wm + i * 16 + fr][fk];
            wf[i] = *(const bf16x8*)((const char*)&Ws[cur][wn + i * 16 + fr][0] + swz);
        }
        #pragma unroll
        for (int i = 0; i < 4; ++i)
            #pragma unroll
            for (int j = 0; j < 4; ++j)
                acc[i][j] = __builtin_amdgcn_mfma_f32_16x16x32_bf16(af[i], wf[j], acc[i][j], 0, 0, 0);

        if (kt + 1 < 16) __syncthreads();
    }

    const int col = lane & 15;
    const int rbase = (lane >> 4) * 4;
    #pragma unroll
    for (int i = 0; i < 4; ++i) {
        #pragma unroll
        for (int j = 0; j < 4; ++j) {
            long long base = (long long)(m0 + wm + i * 16 + rbase) * GN + (n0 + wn + j * 16 + col);
            #pragma unroll
            for (int r = 0; r < 4; ++r)
                C[base + (long long)r * GN] = acc[i][j][r];
        }
    }
}

// ---- fused LIF1 + GEMM2(popcount) + LIF2 ----
// Changes vs R2 (arithmetic identical, bit-identical outputs):
//   * t-unrolled x2: ONE barrier per 2 t (was 1 per t)
//   * barrier_lds() instead of __syncthreads(): no vmcnt(0) store-drain
//   * 2-deep c1 prefetch (t+2, t+3 issued before VALU of t, t+1)
//   * wmks 4-slot dbuf by iteration parity -> still no trailing barrier
__launch_bounds__(512)
__global__ void lif_kernel(const float* __restrict__ cur1, const float* __restrict__ W2,
                           float* __restrict__ out) {
    const int b = blockIdx.x;       // 0..1023
    const int h = threadIdx.x;      // 0..511
    const int w = h >> 6;
    const int lane = h & 63;

    __shared__ unsigned long long wmks[2][2][8];   // [iter parity][t parity][wave]
    __shared__ unsigned long long w2ms[NO][8];

    // build W2 nonzero masks (one-time)
    #pragma unroll
    for (int o = 0; o < NO; ++o) {
        unsigned long long mk = __ballot(W2[o * NH + h] != 0.0f);
        if (lane == 0) w2ms[o][w] = mk;
    }
    __syncthreads();
    unsigned long long w2m[8];
    if (h < NO) {
        #pragma unroll
        for (int i = 0; i < 8; ++i) w2m[i] = w2ms[h][i];
    }

    float m1 = 0.0f, m2 = 0.0f;
    const long long idx1 = (long long)b * NH + h;
    const float* c1p = cur1 + idx1;
    float* s1p = out + S1_OFF + idx1;
    float* m1p = out + M1_OFF + idx1;
    const long long st1 = (long long)BB * NH;   // per-t stride

    float c1a = c1p[0];
    float c1b = c1p[st1];
    for (int t = 0; t < TT; t += 2) {
        const int par = (t >> 1) & 1;

        // 2-deep prefetch: issue t+2, t+3 before any dependent VALU
        float c1c = 0.0f, c1d = 0.0f;
        if (t + 2 < TT) c1c = c1p[(long long)(t + 2) * st1];
        if (t + 3 < TT) c1d = c1p[(long long)(t + 3) * st1];

        // ---- t ----
        float rst = (m1 > 1.0f) ? 1.0f : 0.0f;
        m1 = 0.9f * m1 + c1a - rst;
        float s1a = (m1 > 1.0f) ? 1.0f : 0.0f;
        s1p[(long long)t * st1] = s1a;
        m1p[(long long)t * st1] = m1;
        unsigned long long mka = __ballot(s1a != 0.0f);
        if (lane == 0) wmks[par][0][w] = mka;

        // ---- t+1 ----
        float rstb = (m1 > 1.0f) ? 1.0f : 0.0f;
        m1 = 0.9f * m1 + c1b - rstb;
        float s1b = (m1 > 1.0f) ? 1.0f : 0.0f;
        s1p[(long long)(t + 1) * st1] = s1b;
        m1p[(long long)(t + 1) * st1] = m1;
        unsigned long long mkb = __ballot(s1b != 0.0f);
        if (lane == 0) wmks[par][1][w] = mkb;

        barrier_lds();   // orders the wmks ds_writes only; stores stay in flight

        if (h < NO) {
            #pragma unroll
            for (int j = 0; j < 2; ++j) {
                int cnt = 0;
                #pragma unroll
                for (int i = 0; i < 8; ++i) cnt += __popcll(wmks[par][j][i] & w2m[i]);
                float c2 = 0.5f * (float)cnt;    // exact: multiples of 0.5
                float rst2 = (m2 > 1.0f) ? 1.0f : 0.0f;
                m2 = 0.8f * m2 + c2 - rst2;
                float s2 = (m2 > 1.0f) ? 1.0f : 0.0f;
                long long o2 = (long long)(t + j) * (BB * NO) + b * NO + h;
                out[C2_OFF + o2] = c2;
                out[S2_OFF + o2] = s2;
                out[M2_OFF + o2] = m2;
            }
        }
        c1a = c1c; c1b = c1d;
        // no trailing barrier: wmks double-buffered by iteration parity
    }
}

extern "C" void kernel_launch(void* const* d_in, const int* in_sizes, int n_in,
                              void* d_out, int out_size, void* d_ws, size_t ws_size,
                              hipStream_t stream) {
    const float* x  = (const float*)d_in[0];
    const float* W1 = (const float*)d_in[1];
    const float* W2 = (const float*)d_in[2];
    float* out = (float*)d_out;

    // scratch inside d_out: W image (512KB bf16) at start of spk1 region;
    // consumed by gemm1 before lif_kernel overwrites it (stream-ordered).
    short* Wp = (short*)(out + S1_OFF);
    float* C1 = out + C1_OFF;

    {
        int units = NH * GK / 8;   // 32,768 16B-units
        prep_w_kernel<<<(units + 255) / 256, 256, 0, stream>>>(W1, Wp);
    }
    gemm1_kernel<<<(TB / 128) * (GN / 128), 256, 0, stream>>>(x, Wp, C1);
    lif_kernel<<<BB, NH, 0, stream>>>(C1, W2, out);
}